// Round 9
// baseline (74.303 us; speedup 1.0000x reference)
//
#include <hip/hip_runtime.h>
#include <hip/hip_bf16.h>
#include <math.h>

#define B 2
#define N 1024
#define D 128
#define DA 32
#define NH 4
#define AH 32
#define DEC_H 256
#define DEC_O 128
#define C_DIM ((NH + 1) * D)   // 640
#define TI 32
#define TJ 32
#define SPLIT 8                // j-dimension split for occupancy
#define JCHUNK (N / SPLIT)     // 128

typedef __attribute__((ext_vector_type(8))) short bf16x8;
typedef __attribute__((ext_vector_type(4))) float f32x4;
typedef __attribute__((ext_vector_type(4))) unsigned u32x4;

// round-to-nearest-even f32 -> bf16
static __device__ __forceinline__ unsigned pack2bf(float a, float b) {
    unsigned ua = __float_as_uint(a), ub = __float_as_uint(b);
    unsigned ra = (ua + 0x7FFFu + ((ua >> 16) & 1u)) >> 16;
    unsigned rb = (ub + 0x7FFFu + ((ub >> 16) & 1u)) >> 16;
    return (ra & 0xFFFFu) | (rb << 16);
}
static __device__ __forceinline__ unsigned short tobf(float a) {
    unsigned ua = __float_as_uint(a);
    return (unsigned short)((ua + 0x7FFFu + ((ua >> 16) & 1u)) >> 16);
}

// A-tiled bf16 index for [rows][cols] tiled [mm][kk][16][32]
static __device__ __forceinline__ int atile_idx(int row, int col, int KT) {
    return ((row >> 4) * KT + (col >> 5)) * 512 + (row & 15) * 32 + (col & 31);
}

// ---------------- kernel 1: fused k,q,v projections + hk/hq + pk2/pq2 ----------------
__global__ __launch_bounds__(384) void qkvh_kernel(
    const float* __restrict__ x,
    const float* __restrict__ Wk, const float* __restrict__ bk,
    const float* __restrict__ Wq, const float* __restrict__ bq,
    const float* __restrict__ Wv, const float* __restrict__ bv,
    const float* __restrict__ Wa1, const float* __restrict__ ba1,
    const float* __restrict__ Wa2, const float* __restrict__ ba2,
    float* __restrict__ vBuf, unsigned short* __restrict__ cbfT,
    float* __restrict__ hkOut, float* __restrict__ hqOut,
    float* __restrict__ pkOut, float* __restrict__ pqOut)
{
    const int t = threadIdx.x;
    const int row0 = blockIdx.x * 4;
    __shared__ float xs[4][D];
    __shared__ float kq[2][4][D];
    __shared__ float hls[2][4][NH][DA];

    for (int idx = t; idx < 4 * D; idx += 384)
        xs[idx >> 7][idx & 127] = x[(size_t)row0 * D + idx];
    __syncthreads();

    {   // projections
        const int mat = t >> 7;      // 0=k,1=q,2=v (wave-uniform)
        const int col = t & 127;
        const float* W = (mat == 0) ? Wk : (mat == 1) ? Wq : Wv;
        const float bias = (mat == 0) ? bk[col] : (mat == 1) ? bq[col] : bv[col];
        float a[4];
        #pragma unroll
        for (int m = 0; m < 4; ++m) a[m] = bias;
        for (int d = 0; d < D; ++d) {
            const float w = W[d * D + col];
            #pragma unroll
            for (int m = 0; m < 4; ++m) a[m] = fmaf(xs[m][d], w, a[m]);
        }
        if (mat < 2) {
            #pragma unroll
            for (int m = 0; m < 4; ++m) kq[mat][m][col] = a[m];
        } else {
            #pragma unroll
            for (int m = 0; m < 4; ++m) {
                const int grow = row0 + m;
                vBuf[(size_t)grow * D + col] = a[m];
                cbfT[atile_idx(grow, col, 20)] = tobf(a[m]);
            }
        }
    }
    __syncthreads();

    // hk/hq: 1024 outputs (isq, row, head, a)
    for (int e = t; e < 1024; e += 384) {
        const int isq = e >> 9;
        const int rh = (e >> 7) & 3;
        const int hd = (e >> 5) & 3;
        const int a = e & 31;
        const float* src = &kq[isq][rh][hd * DA];
        const float* W = Wa1 + isq * DA * AH;
        float acc = isq ? ba1[a] : 0.f;
        #pragma unroll
        for (int c = 0; c < DA; ++c)
            acc = fmaf(src[c], W[c * AH + a], acc);
        hls[isq][rh][hd][a] = acc;
        const int grow = row0 + rh;
        const int b = grow >> 10, n = grow & (N - 1);
        float* dst = isq ? hqOut : hkOut;
        dst[(((size_t)(b * NH + hd)) * N + n) * 32 + a] = acc;
    }
    __syncthreads();

    // linear score terms
    if (t < 32) {
        const int isq = t >> 4;
        const int rh = (t >> 2) & 3;
        const int hd = t & 3;
        float p = isq ? 0.f : 2.f * ba2[0];
        #pragma unroll
        for (int a = 0; a < 32; ++a)
            p = fmaf(Wa2[a], hls[isq][rh][hd][a], p);
        const int grow = row0 + rh;
        const int b = grow >> 10, n = grow & (N - 1);
        float* dst = isq ? pqOut : pkOut;
        dst[(size_t)(b * NH + hd) * N + n] = p;
    }
}

// ---------------- kernel 2b: transpose+tile decoder weights to bf16 ----------------
__global__ __launch_bounds__(256) void wtrans_kernel(
    const float* __restrict__ Wd1, const float* __restrict__ Wd2,
    unsigned short* __restrict__ wd1t, unsigned short* __restrict__ wd2t)
{
    const int bid = blockIdx.x, t = threadIdx.x;
    if (bid < 640) {
        const int d = bid;
        wd1t[(d >> 5) * 8192 + t * 32 + (d & 31)] = tobf(Wd1[(size_t)d * 256 + t]);
    } else {
        const int d = bid - 640;
        if (t < 128)
            wd2t[(d >> 5) * 4096 + t * 32 + (d & 31)] = tobf(Wd2[(size_t)d * 128 + t]);
    }
}

// ---------------- kernel 3: attention ----------------
// grid = B*NH*(N/TI)*SPLIT = 2048 blocks x 256 threads.
// hk rows REGISTER-resident (block-invariant; halves score-phase LDS traffic
// vs R8's hks-in-LDS — LDS pipe was the modeled ~20us bottleneck).
// Score via relu-elimination: s' = pk2_i + pq2_j + sum_a Wa2_a*|hk+hq|,
// w = sigmoid(0.5*s'). 2 VALU ops/elem (add + fma-with-|.|). PV via bf16 MFMA.
// launch_bounds (256,4): (256,8) forced VGPR<=32 -> scratch spill (R7).
__global__ __launch_bounds__(256, 4) void attn_kernel(
    const float* __restrict__ hk, const float* __restrict__ hq,
    const float* __restrict__ Wa2,
    const float* __restrict__ pk, const float* __restrict__ pq,
    const float* __restrict__ vBuf, float* __restrict__ pBuf)
{
    const int t = threadIdx.x;
    const int sc = blockIdx.x & (SPLIT - 1);
    const int tile = (blockIdx.x >> 3) & 31;
    const int bh = blockIdx.x >> 8;     // b*NH + h
    const int b = bh >> 2;
    const int i0 = tile * TI;

    __shared__ float hqs[TJ][36];
    __shared__ float pqs[TJ];
    __shared__ unsigned wbf[TI][20];     // bf16 w[i][j]: 80B rows

    // score mapping: rows (ti2, ti2+1), cols (tjA, tjA+16)
    const int ti2 = (t >> 4) << 1;
    const int tjA = t & 15;
    const float pkA = pk[(size_t)bh * N + i0 + ti2];
    const float pkB = pk[(size_t)bh * N + i0 + ti2 + 1];

    // hk rows in registers (block-invariant across the j-loop)
    float4 hkr0[8], hkr1[8];
    {
        const float4* s0 = reinterpret_cast<const float4*>(hk + ((size_t)bh * N + i0 + ti2) * 32);
        const float4* s1 = reinterpret_cast<const float4*>(hk + ((size_t)bh * N + i0 + ti2 + 1) * 32);
        #pragma unroll
        for (int a4 = 0; a4 < 8; ++a4) { hkr0[a4] = s0[a4]; hkr1[a4] = s1[a4]; }
    }

    // mfma mapping
    const int lane = t & 63;
    const int wv = t >> 6;
    const int lm = lane & 15;
    const int lg = lane >> 4;

    f32x4 acc00 = {0.f, 0.f, 0.f, 0.f};
    f32x4 acc01 = {0.f, 0.f, 0.f, 0.f};
    f32x4 acc10 = {0.f, 0.f, 0.f, 0.f};
    f32x4 acc11 = {0.f, 0.f, 0.f, 0.f};

    const int d0 = (2 * wv) * 16 + lm;
    const int d1 = d0 + 16;

    const int jbeg = sc * JCHUNK, jend = jbeg + JCHUNK;
    for (int j0 = jbeg; j0 < jend; j0 += TJ) {
        // stage hq tile + pq slice
        {
            const float* src = hq + ((size_t)bh * N + j0) * 32;
            for (int idx = t; idx < TJ * 32; idx += 256)
                hqs[idx >> 5][idx & 31] = src[idx];
            if (t < TJ) pqs[t] = pq[(size_t)bh * N + j0 + t];
        }
        // issue v fragment loads early (coalesced)
        float v0[8], v1[8];
        {
            const float* vb = vBuf + (size_t)(b * N + j0 + 8 * lg) * D;
            #pragma unroll
            for (int e = 0; e < 8; ++e) {
                v0[e] = vb[(size_t)e * D + d0];
                v1[e] = vb[(size_t)e * D + d1];
            }
        }
        __syncthreads();   // SYNC_A: hqs/pqs ready; prev-iter wbf reads done

        {   // scores: 2x2 per thread; 2 VALU ops per (cell, a)
            float sAA = pkA, sAB = pkA, sBA = pkB, sBB = pkB;
            #pragma unroll
            for (int a4 = 0; a4 < 8; ++a4) {
                const float4 qA = *reinterpret_cast<const float4*>(&hqs[tjA][a4 * 4]);
                const float4 qB = *reinterpret_cast<const float4*>(&hqs[tjA + 16][a4 * 4]);
                const float4 kA = hkr0[a4];
                const float4 kB = hkr1[a4];
                const float4 w4 = reinterpret_cast<const float4*>(Wa2)[a4];
                sAA = fmaf(w4.x, fabsf(kA.x + qA.x), sAA); sAA = fmaf(w4.y, fabsf(kA.y + qA.y), sAA);
                sAA = fmaf(w4.z, fabsf(kA.z + qA.z), sAA); sAA = fmaf(w4.w, fabsf(kA.w + qA.w), sAA);
                sAB = fmaf(w4.x, fabsf(kA.x + qB.x), sAB); sAB = fmaf(w4.y, fabsf(kA.y + qB.y), sAB);
                sAB = fmaf(w4.z, fabsf(kA.z + qB.z), sAB); sAB = fmaf(w4.w, fabsf(kA.w + qB.w), sAB);
                sBA = fmaf(w4.x, fabsf(kB.x + qA.x), sBA); sBA = fmaf(w4.y, fabsf(kB.y + qA.y), sBA);
                sBA = fmaf(w4.z, fabsf(kB.z + qA.z), sBA); sBA = fmaf(w4.w, fabsf(kB.w + qA.w), sBA);
                sBB = fmaf(w4.x, fabsf(kB.x + qB.x), sBB); sBB = fmaf(w4.y, fabsf(kB.y + qB.y), sBB);
                sBB = fmaf(w4.z, fabsf(kB.z + qB.z), sBB); sBB = fmaf(w4.w, fabsf(kB.w + qB.w), sBB);
            }
            sAA += pqs[tjA]; sAB += pqs[tjA + 16];
            sBA += pqs[tjA]; sBB += pqs[tjA + 16];
            const int giA = i0 + ti2, giB = giA + 1;
            const int gjA = j0 + tjA, gjB = gjA + 16;
            if (giA == gjA) sAA -= 20000.f;
            if (giA == gjB) sAB -= 20000.f;
            if (giB == gjA) sBA -= 20000.f;
            if (giB == gjB) sBB -= 20000.f;
            const float wAA = 1.f / (1.f + __expf(-0.5f * sAA));
            const float wAB = 1.f / (1.f + __expf(-0.5f * sAB));
            const float wBA = 1.f / (1.f + __expf(-0.5f * sBA));
            const float wBB = 1.f / (1.f + __expf(-0.5f * sBB));
            unsigned short* wb = reinterpret_cast<unsigned short*>(&wbf[0][0]);
            wb[ti2 * 40 + tjA]            = tobf(wAA);
            wb[ti2 * 40 + tjA + 16]       = tobf(wAB);
            wb[(ti2 + 1) * 40 + tjA]      = tobf(wBA);
            wb[(ti2 + 1) * 40 + tjA + 16] = tobf(wBB);
        }

        // pack v fragments to bf16
        u32x4 pb0, pb1;
        pb0.x = pack2bf(v0[0], v0[1]); pb0.y = pack2bf(v0[2], v0[3]);
        pb0.z = pack2bf(v0[4], v0[5]); pb0.w = pack2bf(v0[6], v0[7]);
        pb1.x = pack2bf(v1[0], v1[1]); pb1.y = pack2bf(v1[2], v1[3]);
        pb1.z = pack2bf(v1[4], v1[5]); pb1.w = pack2bf(v1[6], v1[7]);
        const bf16x8 b0 = __builtin_bit_cast(bf16x8, pb0);
        const bf16x8 b1 = __builtin_bit_cast(bf16x8, pb1);

        __syncthreads();   // SYNC_B: wbf ready

        {   // PV: 4x mfma per wave
            const char* wbase = reinterpret_cast<const char*>(&wbf[0][0]);
            const bf16x8 a0 = *reinterpret_cast<const bf16x8*>(wbase + lm * 80 + lg * 16);
            const bf16x8 a1 = *reinterpret_cast<const bf16x8*>(wbase + (16 + lm) * 80 + lg * 16);
            acc00 = __builtin_amdgcn_mfma_f32_16x16x32_bf16(a0, b0, acc00, 0, 0, 0);
            acc01 = __builtin_amdgcn_mfma_f32_16x16x32_bf16(a0, b1, acc01, 0, 0, 0);
            acc10 = __builtin_amdgcn_mfma_f32_16x16x32_bf16(a1, b0, acc10, 0, 0, 0);
            acc11 = __builtin_amdgcn_mfma_f32_16x16x32_bf16(a1, b1, acc11, 0, 0, 0);
        }
    }

    // write 32x128 partial tile to pBuf[blockIdx.x]
    float* dst = pBuf + (size_t)blockIdx.x * (TI * D);
    #pragma unroll
    for (int r = 0; r < 4; ++r) {
        const int ia = lg * 4 + r;
        dst[ia * D + d0]        = acc00[r];
        dst[ia * D + d1]        = acc01[r];
        dst[(16 + ia) * D + d0] = acc10[r];
        dst[(16 + ia) * D + d1] = acc11[r];
    }
}

// ---------------- kernel 3b: reduce SPLIT partials -> cbfT (bf16 A-tiled) ----------------
__global__ __launch_bounds__(256) void reduce_kernel(
    const float* __restrict__ pBuf, unsigned short* __restrict__ cbfT)
{
    const int e4 = blockIdx.x * 256 + threadIdx.x;   // 0 .. 262143
    const int d4 = e4 & 31;
    const int i = (e4 >> 5) & 31;
    const int tile = (e4 >> 10) & 31;
    const int bh = e4 >> 15;
    const float4* p = reinterpret_cast<const float4*>(pBuf);
    const size_t base = ((size_t)(bh * 32 + tile) * SPLIT) * (TI * D / 4) + i * (D / 4) + d4;
    float4 s = p[base];
    #pragma unroll
    for (int sc = 1; sc < SPLIT; ++sc) {
        const float4 q = p[base + (size_t)sc * (TI * D / 4)];
        s.x += q.x; s.y += q.y; s.z += q.z; s.w += q.w;
    }
    const int b = bh >> 2, h = bh & 3;
    const int grow = b * N + tile * 32 + i;
    const int col0 = (h + 1) * 128 + 4 * d4;
    uint2 pk2;
    pk2.x = pack2bf(s.x, s.y);
    pk2.y = pack2bf(s.z, s.w);
    *reinterpret_cast<uint2*>(cbfT + atile_idx(grow, col0, 20)) = pk2;
}

// ---------------- kernel 4a: decoder layer 1 (bf16 MFMA, no LDS/barriers) ----------------
__global__ __launch_bounds__(256) void dec1_kernel(
    const unsigned short* __restrict__ cbfT, const unsigned short* __restrict__ wd1t,
    const float* __restrict__ bd1, unsigned short* __restrict__ hbfT)
{
    const int t = threadIdx.x;
    const int lane = t & 63, lm = lane & 15, lg = lane >> 4;
    const int wid = blockIdx.x * 4 + (t >> 6);
    const int mm = wid >> 3;         // 0..127
    const int ng = wid & 7;          // 0..7

    f32x4 acc0 = {0.f, 0.f, 0.f, 0.f}, acc1 = {0.f, 0.f, 0.f, 0.f};
    const int abase = mm * 20 * 512 + lm * 32 + lg * 8;
    const int bbase = lm * 32 + lg * 8;
    #pragma unroll 4
    for (int kk = 0; kk < 20; ++kk) {
        const bf16x8 a  = *reinterpret_cast<const bf16x8*>(cbfT + abase + kk * 512);
        const bf16x8 b0 = *reinterpret_cast<const bf16x8*>(wd1t + kk * 8192 + (2 * ng) * 512 + bbase);
        const bf16x8 b1 = *reinterpret_cast<const bf16x8*>(wd1t + kk * 8192 + (2 * ng + 1) * 512 + bbase);
        acc0 = __builtin_amdgcn_mfma_f32_16x16x32_bf16(a, b0, acc0, 0, 0, 0);
        acc1 = __builtin_amdgcn_mfma_f32_16x16x32_bf16(a, b1, acc1, 0, 0, 0);
    }
    const float bias0 = bd1[ng * 32 + lm];
    const float bias1 = bd1[ng * 32 + 16 + lm];
    unsigned short* hb = hbfT + (mm * 8 + ng) * 512;
    #pragma unroll
    for (int r = 0; r < 4; ++r) {
        const int irow = lg * 4 + r;
        hb[irow * 32 + lm]      = tobf(fmaxf(acc0[r] + bias0, 0.f));
        hb[irow * 32 + 16 + lm] = tobf(fmaxf(acc1[r] + bias1, 0.f));
    }
}

// ---------------- kernel 4b: decoder layer 2 ----------------
__global__ __launch_bounds__(256) void dec2_kernel(
    const unsigned short* __restrict__ hbfT, const unsigned short* __restrict__ wd2t,
    const float* __restrict__ bd2, float* __restrict__ out)
{
    const int t = threadIdx.x;
    const int lane = t & 63, lm = lane & 15, lg = lane >> 4;
    const int wid = blockIdx.x * 4 + (t >> 6);   // 0..511
    const int mm = wid >> 2;   // 0..127
    const int og = wid & 3;    // 0..3

    f32x4 acc0 = {0.f, 0.f, 0.f, 0.f}, acc1 = {0.f, 0.f, 0.f, 0.f};
    const int bbase = lm * 32 + lg * 8;
    #pragma unroll
    for (int kk = 0; kk < 8; ++kk) {
        const bf16x8 a  = *reinterpret_cast<const bf16x8*>(hbfT + (mm * 8 + kk) * 512 + bbase);
        const bf16x8 b0 = *reinterpret_cast<const bf16x8*>(wd2t + kk * 4096 + (2 * og) * 512 + bbase);
        const bf16x8 b1 = *reinterpret_cast<const bf16x8*>(wd2t + kk * 4096 + (2 * og + 1) * 512 + bbase);
        acc0 = __builtin_amdgcn_mfma_f32_16x16x32_bf16(a, b0, acc0, 0, 0, 0);
        acc1 = __builtin_amdgcn_mfma_f32_16x16x32_bf16(a, b1, acc1, 0, 0, 0);
    }
    const float bias0 = bd2[og * 32 + lm];
    const float bias1 = bd2[og * 32 + 16 + lm];
    float* op = out + (size_t)(mm * 16) * DEC_O;
    #pragma unroll
    for (int r = 0; r < 4; ++r) {
        const int irow = lg * 4 + r;
        op[irow * DEC_O + og * 32 + lm]      = acc0[r] + bias0;
        op[irow * DEC_O + og * 32 + 16 + lm] = acc1[r] + bias1;
    }
}

extern "C" void kernel_launch(void* const* d_in, const int* in_sizes, int n_in,
                              void* d_out, int out_size, void* d_ws, size_t ws_size,
                              hipStream_t stream)
{
    const float* x   = (const float*)d_in[0];
    const float* Wk  = (const float*)d_in[1];
    const float* bk  = (const float*)d_in[2];
    const float* Wq  = (const float*)d_in[3];
    const float* bq  = (const float*)d_in[4];
    const float* Wv  = (const float*)d_in[5];
    const float* bv  = (const float*)d_in[6];
    const float* Wa1 = (const float*)d_in[7];
    const float* ba1 = (const float*)d_in[8];
    const float* Wa2 = (const float*)d_in[9];
    const float* ba2 = (const float*)d_in[10];
    const float* Wd1 = (const float*)d_in[11];
    const float* bd1 = (const float*)d_in[12];
    const float* Wd2 = (const float*)d_in[13];
    const float* bd2 = (const float*)d_in[14];
    float* out = (float*)d_out;

    float* ws = (float*)d_ws;
    float* hkBuf = ws;                        // 262144
    float* hqBuf = hkBuf + 262144;            // 262144
    float* vBuf  = hqBuf + 262144;            // 262144
    float* pkBuf = vBuf + 262144;             // 8192
    float* pqBuf = pkBuf + 8192;              // 8192
    float* pBuf  = pqBuf + 8192;              // 2048*4096 = 8388608
    unsigned short* cbfT = (unsigned short*)(pBuf + 8388608);  // 1310720 u16
    unsigned short* hbfT = cbfT + 1310720;                     // 524288 u16
    unsigned short* wd1t = hbfT + 524288;                      // 163840 u16
    unsigned short* wd2t = wd1t + 163840;                      // 32768 u16

    qkvh_kernel<<<B * N / 4, 384, 0, stream>>>(x, Wk, bk, Wq, bq, Wv, bv, Wa1, ba1, Wa2, ba2,
                                               vBuf, cbfT, hkBuf, hqBuf, pkBuf, pqBuf);
    wtrans_kernel<<<896, 256, 0, stream>>>(Wd1, Wd2, wd1t, wd2t);
    attn_kernel<<<B * NH * (N / TI) * SPLIT, 256, 0, stream>>>(hkBuf, hqBuf, Wa2, pkBuf, pqBuf, vBuf, pBuf);
    reduce_kernel<<<1024, 256, 0, stream>>>(pBuf, cbfT);
    dec1_kernel<<<256, 256, 0, stream>>>(cbfT, wd1t, bd1, hbfT);
    dec2_kernel<<<128, 256, 0, stream>>>(hbfT, wd2t, bd2, out);
}

// Round 10
// 64.566 us; speedup vs baseline: 1.1508x; 1.1508x over previous
//
#include <hip/hip_runtime.h>
#include <hip/hip_bf16.h>
#include <math.h>

#define B 2
#define N 1024
#define D 128
#define DA 32
#define NH 4
#define AH 32
#define DEC_H 256
#define DEC_O 128
#define C_DIM ((NH + 1) * D)   // 640
#define TI 32
#define TJ 32
#define SPLIT 4                // j-dimension split
#define JCHUNK (N / SPLIT)     // 256 -> 8 j-tiles per block

typedef __attribute__((ext_vector_type(8))) short bf16x8;
typedef __attribute__((ext_vector_type(4))) float f32x4;

// round-to-nearest-even f32 -> bf16
static __device__ __forceinline__ unsigned pack2bf(float a, float b) {
    unsigned ua = __float_as_uint(a), ub = __float_as_uint(b);
    unsigned ra = (ua + 0x7FFFu + ((ua >> 16) & 1u)) >> 16;
    unsigned rb = (ub + 0x7FFFu + ((ub >> 16) & 1u)) >> 16;
    return (ra & 0xFFFFu) | (rb << 16);
}
static __device__ __forceinline__ unsigned short tobf(float a) {
    unsigned ua = __float_as_uint(a);
    return (unsigned short)((ua + 0x7FFFu + ((ua >> 16) & 1u)) >> 16);
}

// A-tiled bf16 index for [rows][cols] tiled [mm][kk][16][32]
static __device__ __forceinline__ int atile_idx(int row, int col, int KT) {
    return ((row >> 4) * KT + (col >> 5)) * 512 + (row & 15) * 32 + (col & 31);
}

// ---------------- kernel 1: fused k,q,v projections + hk/hq + pk2/pq2 ----------------
// v emitted as: cbfT (bf16 A-tiled, decoder input) and vT8 (bf16, B-frag-ready
// layout [b][j>>3][d][j&7] so attn loads MFMA B operands with one dwordx4).
__global__ __launch_bounds__(384) void qkvh_kernel(
    const float* __restrict__ x,
    const float* __restrict__ Wk, const float* __restrict__ bk,
    const float* __restrict__ Wq, const float* __restrict__ bq,
    const float* __restrict__ Wv, const float* __restrict__ bv,
    const float* __restrict__ Wa1, const float* __restrict__ ba1,
    const float* __restrict__ Wa2, const float* __restrict__ ba2,
    unsigned short* __restrict__ vT8, unsigned short* __restrict__ cbfT,
    float* __restrict__ hkOut, float* __restrict__ hqOut,
    float* __restrict__ pkOut, float* __restrict__ pqOut)
{
    const int t = threadIdx.x;
    const int row0 = blockIdx.x * 4;
    __shared__ float xs[4][D];
    __shared__ float kq[2][4][D];
    __shared__ float hls[2][4][NH][DA];

    for (int idx = t; idx < 4 * D; idx += 384)
        xs[idx >> 7][idx & 127] = x[(size_t)row0 * D + idx];
    __syncthreads();

    {   // projections
        const int mat = t >> 7;      // 0=k,1=q,2=v (wave-uniform)
        const int col = t & 127;
        const float* W = (mat == 0) ? Wk : (mat == 1) ? Wq : Wv;
        const float bias = (mat == 0) ? bk[col] : (mat == 1) ? bq[col] : bv[col];
        float a[4];
        #pragma unroll
        for (int m = 0; m < 4; ++m) a[m] = bias;
        for (int d = 0; d < D; ++d) {
            const float w = W[d * D + col];
            #pragma unroll
            for (int m = 0; m < 4; ++m) a[m] = fmaf(xs[m][d], w, a[m]);
        }
        if (mat < 2) {
            #pragma unroll
            for (int m = 0; m < 4; ++m) kq[mat][m][col] = a[m];
        } else {
            #pragma unroll
            for (int m = 0; m < 4; ++m)
                cbfT[atile_idx(row0 + m, col, 20)] = tobf(a[m]);
            // vT8: rows row0..row0+3 are contiguous e-slots within one j/8 block
            const int b = row0 >> 10, n = row0 & (N - 1);
            uint2 pk2;
            pk2.x = pack2bf(a[0], a[1]);
            pk2.y = pack2bf(a[2], a[3]);
            unsigned short* dst = vT8 + (((size_t)b * (N >> 3) + (n >> 3)) * D + col) * 8 + (n & 7);
            *reinterpret_cast<uint2*>(dst) = pk2;
        }
    }
    __syncthreads();

    // hk/hq: 1024 outputs (isq, row, head, a)
    for (int e = t; e < 1024; e += 384) {
        const int isq = e >> 9;
        const int rh = (e >> 7) & 3;
        const int hd = (e >> 5) & 3;
        const int a = e & 31;
        const float* src = &kq[isq][rh][hd * DA];
        const float* W = Wa1 + isq * DA * AH;
        float acc = isq ? ba1[a] : 0.f;
        #pragma unroll
        for (int c = 0; c < DA; ++c)
            acc = fmaf(src[c], W[c * AH + a], acc);
        hls[isq][rh][hd][a] = acc;
        const int grow = row0 + rh;
        const int b = grow >> 10, n = grow & (N - 1);
        float* dst = isq ? hqOut : hkOut;
        dst[(((size_t)(b * NH + hd)) * N + n) * 32 + a] = acc;
    }
    __syncthreads();

    // linear score terms: pk2 = sum_a Wa2*hk + 2*ba2 ; pq2 = sum_a Wa2*hq
    if (t < 32) {
        const int isq = t >> 4;
        const int rh = (t >> 2) & 3;
        const int hd = t & 3;
        float p = isq ? 0.f : 2.f * ba2[0];
        #pragma unroll
        for (int a = 0; a < 32; ++a)
            p = fmaf(Wa2[a], hls[isq][rh][hd][a], p);
        const int grow = row0 + rh;
        const int b = grow >> 10, n = grow & (N - 1);
        float* dst = isq ? pqOut : pkOut;
        dst[(size_t)(b * NH + hd) * N + n] = p;
    }
}

// ---------------- kernel 2b: transpose+tile decoder weights to bf16 ----------------
__global__ __launch_bounds__(256) void wtrans_kernel(
    const float* __restrict__ Wd1, const float* __restrict__ Wd2,
    unsigned short* __restrict__ wd1t, unsigned short* __restrict__ wd2t)
{
    const int bid = blockIdx.x, t = threadIdx.x;
    if (bid < 640) {
        const int d = bid;
        wd1t[(d >> 5) * 8192 + t * 32 + (d & 31)] = tobf(Wd1[(size_t)d * 256 + t]);
    } else {
        const int d = bid - 640;
        if (t < 128)
            wd2t[(d >> 5) * 4096 + t * 32 + (d & 31)] = tobf(Wd2[(size_t)d * 128 + t]);
    }
}

// ---------------- kernel 3: attention ----------------
// grid = B*NH*(N/TI)*SPLIT = 1024 blocks x 256 threads.
// Overhead-minimized j-loop: ONE barrier/iter (double-buffered hqs+wbf),
// B-frags loaded directly as bf16 dwordx4 from vT8 (no packing), pq via
// 2 scalar L2 loads, hk broadcast-read from LDS (no phantom 64-reg array).
// Score: s' = pk2_i + pq2_j + sum_a Wa2_a*|hk+hq| ; w = sigmoid(0.5*s').
__global__ __launch_bounds__(256, 4) void attn_kernel(
    const float* __restrict__ hk, const float* __restrict__ hq,
    const float* __restrict__ Wa2,
    const float* __restrict__ pk, const float* __restrict__ pq,
    const unsigned short* __restrict__ vT8, float* __restrict__ pBuf)
{
    const int t = threadIdx.x;
    const int sc = blockIdx.x & (SPLIT - 1);
    const int tile = (blockIdx.x >> 2) & 31;
    const int bh = blockIdx.x >> 7;     // b*NH + h
    const int b = bh >> 2;
    const int i0 = tile * TI;

    __shared__ float hks[TI][36];
    __shared__ float hqs[2][TJ][36];
    __shared__ unsigned wbf[2][TI][20];   // bf16 w[i][j], 80B rows

    const int ti2 = (t >> 4) << 1;
    const int tjA = t & 15;
    const float pkA = pk[(size_t)bh * N + i0 + ti2];
    const float pkB = pk[(size_t)bh * N + i0 + ti2 + 1];

    const int lane = t & 63;
    const int wv = t >> 6;
    const int lm = lane & 15;
    const int lg = lane >> 4;
    const int d0 = (2 * wv) * 16 + lm;
    const int d1 = d0 + 16;

    f32x4 acc00 = {0.f, 0.f, 0.f, 0.f};
    f32x4 acc01 = {0.f, 0.f, 0.f, 0.f};
    f32x4 acc10 = {0.f, 0.f, 0.f, 0.f};
    f32x4 acc11 = {0.f, 0.f, 0.f, 0.f};

    const int jbeg = sc * JCHUNK;
    {   // prologue: stage hks + hqs[0]
        const float* srck = hk + ((size_t)bh * N + i0) * 32;
        const float* srcq = hq + ((size_t)bh * N + jbeg) * 32;
        for (int idx = t; idx < TI * 32; idx += 256) {
            hks[idx >> 5][idx & 31] = srck[idx];
            hqs[0][idx >> 5][idx & 31] = srcq[idx];
        }
    }
    __syncthreads();

    #pragma unroll 2
    for (int it = 0; it < JCHUNK / TJ; ++it) {
        const int j0 = jbeg + it * TJ;
        const int cur = it & 1;

        // MFMA B-frags direct from vT8 (256B-contiguous per lg-group)
        const unsigned short* vb = vT8 + (((size_t)b * (N >> 3) + (j0 >> 3) + lg) * D) * 8;
        const bf16x8 b0 = *reinterpret_cast<const bf16x8*>(vb + d0 * 8);
        const bf16x8 b1 = *reinterpret_cast<const bf16x8*>(vb + d1 * 8);
        const float pqA = pq[(size_t)bh * N + j0 + tjA];
        const float pqB = pq[(size_t)bh * N + j0 + tjA + 16];

        {   // scores: 2x2 per thread; 2 VALU ops per (cell, a)
            float sAA = pkA, sAB = pkA, sBA = pkB, sBB = pkB;
            #pragma unroll
            for (int a4 = 0; a4 < 8; ++a4) {
                const float4 kA = *reinterpret_cast<const float4*>(&hks[ti2][a4 * 4]);
                const float4 kB = *reinterpret_cast<const float4*>(&hks[ti2 + 1][a4 * 4]);
                const float4 qA = *reinterpret_cast<const float4*>(&hqs[cur][tjA][a4 * 4]);
                const float4 qB = *reinterpret_cast<const float4*>(&hqs[cur][tjA + 16][a4 * 4]);
                const float4 w4 = reinterpret_cast<const float4*>(Wa2)[a4];
                sAA = fmaf(w4.x, fabsf(kA.x + qA.x), sAA); sAA = fmaf(w4.y, fabsf(kA.y + qA.y), sAA);
                sAA = fmaf(w4.z, fabsf(kA.z + qA.z), sAA); sAA = fmaf(w4.w, fabsf(kA.w + qA.w), sAA);
                sAB = fmaf(w4.x, fabsf(kA.x + qB.x), sAB); sAB = fmaf(w4.y, fabsf(kA.y + qB.y), sAB);
                sAB = fmaf(w4.z, fabsf(kA.z + qB.z), sAB); sAB = fmaf(w4.w, fabsf(kA.w + qB.w), sAB);
                sBA = fmaf(w4.x, fabsf(kB.x + qA.x), sBA); sBA = fmaf(w4.y, fabsf(kB.y + qA.y), sBA);
                sBA = fmaf(w4.z, fabsf(kB.z + qA.z), sBA); sBA = fmaf(w4.w, fabsf(kB.w + qA.w), sBA);
                sBB = fmaf(w4.x, fabsf(kB.x + qB.x), sBB); sBB = fmaf(w4.y, fabsf(kB.y + qB.y), sBB);
                sBB = fmaf(w4.z, fabsf(kB.z + qB.z), sBB); sBB = fmaf(w4.w, fabsf(kB.w + qB.w), sBB);
            }
            sAA += pqA; sAB += pqB; sBA += pqA; sBB += pqB;
            const int giA = i0 + ti2, giB = giA + 1;
            const int gjA = j0 + tjA, gjB = gjA + 16;
            if (giA == gjA) sAA -= 20000.f;
            if (giA == gjB) sAB -= 20000.f;
            if (giB == gjA) sBA -= 20000.f;
            if (giB == gjB) sBB -= 20000.f;
            const float wAA = 1.f / (1.f + __expf(-0.5f * sAA));
            const float wAB = 1.f / (1.f + __expf(-0.5f * sAB));
            const float wBA = 1.f / (1.f + __expf(-0.5f * sBA));
            const float wBB = 1.f / (1.f + __expf(-0.5f * sBB));
            unsigned short* wb = reinterpret_cast<unsigned short*>(&wbf[cur][0][0]);
            wb[ti2 * 40 + tjA]            = tobf(wAA);
            wb[ti2 * 40 + tjA + 16]       = tobf(wAB);
            wb[(ti2 + 1) * 40 + tjA]      = tobf(wBA);
            wb[(ti2 + 1) * 40 + tjA + 16] = tobf(wBB);
        }

        // stage next iter's hq into the other buffer
        if (it + 1 < JCHUNK / TJ) {
            const float* srcq = hq + ((size_t)bh * N + j0 + TJ) * 32;
            for (int idx = t; idx < TJ * 32; idx += 256)
                hqs[cur ^ 1][idx >> 5][idx & 31] = srcq[idx];
        }

        __syncthreads();   // wbf[cur] ready for all waves; hqs[cur^1] staged

        {   // PV: 4x mfma per wave
            const char* wbase = reinterpret_cast<const char*>(&wbf[cur][0][0]);
            const bf16x8 a0 = *reinterpret_cast<const bf16x8*>(wbase + lm * 80 + lg * 16);
            const bf16x8 a1 = *reinterpret_cast<const bf16x8*>(wbase + (16 + lm) * 80 + lg * 16);
            acc00 = __builtin_amdgcn_mfma_f32_16x16x32_bf16(a0, b0, acc00, 0, 0, 0);
            acc01 = __builtin_amdgcn_mfma_f32_16x16x32_bf16(a0, b1, acc01, 0, 0, 0);
            acc10 = __builtin_amdgcn_mfma_f32_16x16x32_bf16(a1, b0, acc10, 0, 0, 0);
            acc11 = __builtin_amdgcn_mfma_f32_16x16x32_bf16(a1, b1, acc11, 0, 0, 0);
        }
    }

    // write 32x128 partial tile to pBuf[blockIdx.x]
    float* dst = pBuf + (size_t)blockIdx.x * (TI * D);
    #pragma unroll
    for (int r = 0; r < 4; ++r) {
        const int ia = lg * 4 + r;
        dst[ia * D + d0]        = acc00[r];
        dst[ia * D + d1]        = acc01[r];
        dst[(16 + ia) * D + d0] = acc10[r];
        dst[(16 + ia) * D + d1] = acc11[r];
    }
}

// ---------------- kernel 3b: reduce SPLIT partials -> cbfT (bf16 A-tiled) ----------------
__global__ __launch_bounds__(256) void reduce_kernel(
    const float* __restrict__ pBuf, unsigned short* __restrict__ cbfT)
{
    const int e4 = blockIdx.x * 256 + threadIdx.x;   // 0 .. 262143
    const int d4 = e4 & 31;
    const int i = (e4 >> 5) & 31;
    const int tile = (e4 >> 10) & 31;
    const int bh = e4 >> 15;
    const float4* p = reinterpret_cast<const float4*>(pBuf);
    const size_t base = ((size_t)(bh * 32 + tile) * SPLIT) * (TI * D / 4) + i * (D / 4) + d4;
    float4 s = p[base];
    #pragma unroll
    for (int sc = 1; sc < SPLIT; ++sc) {
        const float4 q = p[base + (size_t)sc * (TI * D / 4)];
        s.x += q.x; s.y += q.y; s.z += q.z; s.w += q.w;
    }
    const int b = bh >> 2, h = bh & 3;
    const int grow = b * N + tile * 32 + i;
    const int col0 = (h + 1) * 128 + 4 * d4;
    uint2 pk2;
    pk2.x = pack2bf(s.x, s.y);
    pk2.y = pack2bf(s.z, s.w);
    *reinterpret_cast<uint2*>(cbfT + atile_idx(grow, col0, 20)) = pk2;
}

// ---------------- kernel 4a: decoder layer 1 (bf16 MFMA, no LDS/barriers) ----------------
__global__ __launch_bounds__(256) void dec1_kernel(
    const unsigned short* __restrict__ cbfT, const unsigned short* __restrict__ wd1t,
    const float* __restrict__ bd1, unsigned short* __restrict__ hbfT)
{
    const int t = threadIdx.x;
    const int lane = t & 63, lm = lane & 15, lg = lane >> 4;
    const int wid = blockIdx.x * 4 + (t >> 6);
    const int mm = wid >> 3;         // 0..127
    const int ng = wid & 7;          // 0..7

    f32x4 acc0 = {0.f, 0.f, 0.f, 0.f}, acc1 = {0.f, 0.f, 0.f, 0.f};
    const int abase = mm * 20 * 512 + lm * 32 + lg * 8;
    const int bbase = lm * 32 + lg * 8;
    #pragma unroll 4
    for (int kk = 0; kk < 20; ++kk) {
        const bf16x8 a  = *reinterpret_cast<const bf16x8*>(cbfT + abase + kk * 512);
        const bf16x8 b0 = *reinterpret_cast<const bf16x8*>(wd1t + kk * 8192 + (2 * ng) * 512 + bbase);
        const bf16x8 b1 = *reinterpret_cast<const bf16x8*>(wd1t + kk * 8192 + (2 * ng + 1) * 512 + bbase);
        acc0 = __builtin_amdgcn_mfma_f32_16x16x32_bf16(a, b0, acc0, 0, 0, 0);
        acc1 = __builtin_amdgcn_mfma_f32_16x16x32_bf16(a, b1, acc1, 0, 0, 0);
    }
    const float bias0 = bd1[ng * 32 + lm];
    const float bias1 = bd1[ng * 32 + 16 + lm];
    unsigned short* hb = hbfT + (mm * 8 + ng) * 512;
    #pragma unroll
    for (int r = 0; r < 4; ++r) {
        const int irow = lg * 4 + r;
        hb[irow * 32 + lm]      = tobf(fmaxf(acc0[r] + bias0, 0.f));
        hb[irow * 32 + 16 + lm] = tobf(fmaxf(acc1[r] + bias1, 0.f));
    }
}

// ---------------- kernel 4b: decoder layer 2 ----------------
__global__ __launch_bounds__(256) void dec2_kernel(
    const unsigned short* __restrict__ hbfT, const unsigned short* __restrict__ wd2t,
    const float* __restrict__ bd2, float* __restrict__ out)
{
    const int t = threadIdx.x;
    const int lane = t & 63, lm = lane & 15, lg = lane >> 4;
    const int wid = blockIdx.x * 4 + (t >> 6);   // 0..511
    const int mm = wid >> 2;   // 0..127
    const int og = wid & 3;    // 0..3

    f32x4 acc0 = {0.f, 0.f, 0.f, 0.f}, acc1 = {0.f, 0.f, 0.f, 0.f};
    const int bbase = lm * 32 + lg * 8;
    #pragma unroll
    for (int kk = 0; kk < 8; ++kk) {
        const bf16x8 a  = *reinterpret_cast<const bf16x8*>(hbfT + (mm * 8 + kk) * 512 + bbase);
        const bf16x8 b0 = *reinterpret_cast<const bf16x8*>(wd2t + kk * 4096 + (2 * og) * 512 + bbase);
        const bf16x8 b1 = *reinterpret_cast<const bf16x8*>(wd2t + kk * 4096 + (2 * og + 1) * 512 + bbase);
        acc0 = __builtin_amdgcn_mfma_f32_16x16x32_bf16(a, b0, acc0, 0, 0, 0);
        acc1 = __builtin_amdgcn_mfma_f32_16x16x32_bf16(a, b1, acc1, 0, 0, 0);
    }
    const float bias0 = bd2[og * 32 + lm];
    const float bias1 = bd2[og * 32 + 16 + lm];
    float* op = out + (size_t)(mm * 16) * DEC_O;
    #pragma unroll
    for (int r = 0; r < 4; ++r) {
        const int irow = lg * 4 + r;
        op[irow * DEC_O + og * 32 + lm]      = acc0[r] + bias0;
        op[irow * DEC_O + og * 32 + 16 + lm] = acc1[r] + bias1;
    }
}

extern "C" void kernel_launch(void* const* d_in, const int* in_sizes, int n_in,
                              void* d_out, int out_size, void* d_ws, size_t ws_size,
                              hipStream_t stream)
{
    const float* x   = (const float*)d_in[0];
    const float* Wk  = (const float*)d_in[1];
    const float* bk  = (const float*)d_in[2];
    const float* Wq  = (const float*)d_in[3];
    const float* bq  = (const float*)d_in[4];
    const float* Wv  = (const float*)d_in[5];
    const float* bv  = (const float*)d_in[6];
    const float* Wa1 = (const float*)d_in[7];
    const float* ba1 = (const float*)d_in[8];
    const float* Wa2 = (const float*)d_in[9];
    const float* ba2 = (const float*)d_in[10];
    const float* Wd1 = (const float*)d_in[11];
    const float* bd1 = (const float*)d_in[12];
    const float* Wd2 = (const float*)d_in[13];
    const float* bd2 = (const float*)d_in[14];
    float* out = (float*)d_out;

    float* ws = (float*)d_ws;
    float* hkBuf = ws;                        // 262144 f32
    float* hqBuf = hkBuf + 262144;            // 262144 f32
    float* pkBuf = hqBuf + 262144;            // 8192 f32
    float* pqBuf = pkBuf + 8192;              // 8192 f32
    float* pBuf  = pqBuf + 8192;              // 1024*4096 f32 = 16 MB
    unsigned short* cbfT = (unsigned short*)(pBuf + 4194304);  // 1310720 u16
    unsigned short* hbfT = cbfT + 1310720;                     // 524288 u16
    unsigned short* wd1t = hbfT + 524288;                      // 163840 u16
    unsigned short* wd2t = wd1t + 163840;                      // 32768 u16
    unsigned short* vT8  = wd2t + 32768;                       // 262144 u16

    qkvh_kernel<<<B * N / 4, 384, 0, stream>>>(x, Wk, bk, Wq, bq, Wv, bv, Wa1, ba1, Wa2, ba2,
                                               vT8, cbfT, hkBuf, hqBuf, pkBuf, pqBuf);
    wtrans_kernel<<<896, 256, 0, stream>>>(Wd1, Wd2, wd1t, wd2t);
    attn_kernel<<<B * NH * (N / TI) * SPLIT, 256, 0, stream>>>(hkBuf, hqBuf, Wa2, pkBuf, pqBuf, vT8, pBuf);
    reduce_kernel<<<1024, 256, 0, stream>>>(pBuf, cbfT);
    dec1_kernel<<<256, 256, 0, stream>>>(cbfT, wd1t, bd1, hbfT);
    dec2_kernel<<<128, 256, 0, stream>>>(hbfT, wd2t, bd2, out);
}